// Round 6
// baseline (51545.325 us; speedup 1.0000x reference)
//
#include <hip/hip_runtime.h>
#include <cmath>

#define NB   256
#define NT   64
#define DATA 256
#define DD   264
#define DDP  272     // W0 rows padded to 272 floats (1088B, 64B-aligned)
#define WID  256
#define NSUB 4
#define NTH  512

// d_ws float offsets
#define WS_W0P 0                      // [256][272] padded row-major W0
#define WS_W1T (WS_W0P + 256 * DDP)   // [256][256] k-major W1 (W1T[k][j] = W1[j][k])
#define WS_W2T (WS_W1T + 256 * 256)   // [256][256] k-major W2

// LDS layout (float offsets)
#define NK_LDS 136
#define L_W1LO 0                         // [136][256] = 34816
#define L_PS   (L_W1LO + NK_LDS * 256)   // [8][256]   = 2048
#define L_Y    (L_PS + 8 * 256)          // 272 (pads zero)
#define L_IN   (L_Y + DDP)               // 272 (pads zero)
#define L_K    (L_IN + DDP)              // 272
#define L_ACC  (L_K + DDP)               // 272
#define L_HA   (L_ACC + DDP)             // 272
#define L_HB   (L_HA + DDP)              // 272
#define L_B0   (L_HB + DDP)              // 256
#define L_B1   (L_B0 + 256)              // 256
#define L_B2   (L_B1 + 256)              // 256
#define L_B3   (L_B2 + 256)              // 264 (reserve 272)
#define LDS_FLOATS (L_B3 + DDP)          // 39536 floats = 158,144 B -> 1 block/CU

__global__ void prep(const float* __restrict__ W0, const float* __restrict__ W1,
                     const float* __restrict__ W2, float* __restrict__ ws) {
  int tid = blockIdx.x * blockDim.x + threadIdx.x;
  int stride = gridDim.x * blockDim.x;
  for (int i = tid; i < 256 * DDP; i += stride) {
    int j = i / DDP, m = i - j * DDP;
    ws[WS_W0P + i] = (m < DD) ? W0[j * DD + m] : 0.f;
  }
  for (int i = tid; i < 256 * 256; i += stride) {
    int k = i >> 8, j = i & 255;
    ws[WS_W1T + i] = W1[j * 256 + k];
    ws[WS_W2T + i] = W2[j * 256 + k];
  }
}

// __launch_bounds__(512, 1): 1 block/CU (the 158KB LDS forces this anyway)
// -> 2 waves/SIMD -> 256-VGPR cap. (512,2) was honored as 2 blocks/CU ->
// 128-VGPR cap, which spilled the 188-reg weight cache to scratch (R4/R5:
// VGPR_Count=128, 78.6GB FETCH of pure spill traffic).
__global__ __launch_bounds__(NTH, 1) void node_integrate(
    const float* __restrict__ ts, const float* __restrict__ xs,
    const float* __restrict__ a_sample,
    const float* __restrict__ b0g, const float* __restrict__ b1g,
    const float* __restrict__ b2g, const float* __restrict__ b3g,
    const float* __restrict__ W3, const float* __restrict__ ws,
    float* __restrict__ out) {
  extern __shared__ float sm[];
  const int b   = blockIdx.x;
  const int tid = threadIdx.x;
  const int w   = tid >> 6;   // wave 0..7
  const int l   = tid & 63;   // lane
  const int rr  = l >> 2;     // row-slot 0..15
  const int c   = l & 3;      // quarter-row 0..3

  // ---- one-time fills ----
  for (int i = tid; i < WID; i += NTH) {
    sm[L_B0 + i] = b0g[i];
    sm[L_B1 + i] = b1g[i];
    sm[L_B2 + i] = b2g[i];
  }
  for (int i = tid; i < DD; i += NTH) sm[L_B3 + i] = b3g[i];
  {
    const float4* src = (const float4*)(ws + WS_W1T);
    float4* dst = (float4*)(sm + L_W1LO);
    for (int i = tid; i < NK_LDS * 64; i += NTH) dst[i] = src[i];
  }
  // Register-resident weights: literal-indexed only, never passed anywhere.
  float4 w1r[15];   // W1 k = 136 + w + 8i
  float4 w2r[32];   // W2 k = w + 8i
  {
    const float4* w1t = (const float4*)(ws + WS_W1T);
    const float4* w2t = (const float4*)(ws + WS_W2T);
#pragma unroll
    for (int i = 0; i < 15; ++i) w1r[i] = w1t[(NK_LDS + w + 8 * i) * 64 + l];
#pragma unroll
    for (int i = 0; i < 32; ++i) w2r[i] = w2t[(w + 8 * i) * 64 + l];
  }
  // y0 = concat(a * exp(-0.1*t0) * sin(pi*x), zeros(AUG)); pads [264,272) = 0
  if (tid < DDP) {
    float v = 0.f;
    if (tid < DATA) {
      float x = xs[(size_t)b * DATA + tid];
      float scale = a_sample[b] * expf(-0.1f * ts[0]);
      v = scale * sinf(3.14159265358979323846f * x);
    }
    sm[L_Y + tid]  = v;
    sm[L_IN + tid] = 0.f;
  }
  __syncthreads();

  if (tid < DATA) out[((size_t)b * NT) * DATA + tid] = sm[L_Y + tid];

  const float* W0p = ws + WS_W0P;

#pragma unroll 1
  for (int t = 0; t < NT - 1; ++t) {
    const float dt = ts[t + 1] - ts[t];
    const float h  = dt * (1.0f / NSUB);
#pragma unroll 1
    for (int sub = 0; sub < NSUB; ++sub) {
#pragma unroll 1
      for (int s = 0; s < 3; ++s) {
        const float4* fin4 = (const float4*)(sm + ((s == 0) ? L_Y : L_IN));

        // ---- L0: hA = tanh(W0 @ fin + b0); streamed, 16 rows x 64B per instr
#pragma unroll
        for (int ch = 0; ch < 2; ++ch) {
          const int j = w + 8 * (16 * ch + rr);
          const float4* wr = (const float4*)(W0p + j * DDP);
          float acc = 0.f;
#pragma unroll
          for (int it = 0; it < 17; ++it) {
            float4 wv = wr[4 * it + c];
            float4 fv = fin4[4 * it + c];
            acc = fmaf(wv.x, fv.x, acc);
            acc = fmaf(wv.y, fv.y, acc);
            acc = fmaf(wv.z, fv.z, acc);
            acc = fmaf(wv.w, fv.w, acc);
          }
          acc += __shfl_xor(acc, 1);
          acc += __shfl_xor(acc, 2);
          if (c == 0) sm[L_HA + j] = tanhf(acc + sm[L_B0 + j]);
        }
        __syncthreads();

        // ---- L1: hB = tanh(W1 @ hA + b1); LDS k<136, regs k>=136
        {
          float4 acc;
          acc.x = acc.y = acc.z = acc.w = 0.f;
#pragma unroll
          for (int i = 0; i < 17; ++i) {
            const int k = w + 8 * i;                       // < 136
            const float fk = sm[L_HA + k];
            const float4 wv = ((const float4*)(sm + L_W1LO))[k * 64 + l];
            acc.x = fmaf(wv.x, fk, acc.x);
            acc.y = fmaf(wv.y, fk, acc.y);
            acc.z = fmaf(wv.z, fk, acc.z);
            acc.w = fmaf(wv.w, fk, acc.w);
          }
#pragma unroll
          for (int i = 0; i < 15; ++i) {
            const float fk = sm[L_HA + NK_LDS + w + 8 * i];
            acc.x = fmaf(w1r[i].x, fk, acc.x);
            acc.y = fmaf(w1r[i].y, fk, acc.y);
            acc.z = fmaf(w1r[i].z, fk, acc.z);
            acc.w = fmaf(w1r[i].w, fk, acc.w);
          }
          ((float4*)(sm + L_PS + w * WID))[l] = acc;
        }
        __syncthreads();
        if (tid < WID) {
          float sacc = sm[L_B1 + tid];
#pragma unroll
          for (int ww = 0; ww < 8; ++ww) sacc += sm[L_PS + ww * WID + tid];
          sm[L_HB + tid] = tanhf(sacc);
        }
        __syncthreads();

        // ---- L2: hA = tanh(W2 @ hB + b2); all-register
        {
          float4 acc;
          acc.x = acc.y = acc.z = acc.w = 0.f;
#pragma unroll
          for (int i = 0; i < 32; ++i) {
            const float fk = sm[L_HB + w + 8 * i];
            acc.x = fmaf(w2r[i].x, fk, acc.x);
            acc.y = fmaf(w2r[i].y, fk, acc.y);
            acc.z = fmaf(w2r[i].z, fk, acc.z);
            acc.w = fmaf(w2r[i].w, fk, acc.w);
          }
          ((float4*)(sm + L_PS + w * WID))[l] = acc;
        }
        __syncthreads();
        if (tid < WID) {
          float sacc = sm[L_B2 + tid];
#pragma unroll
          for (int ww = 0; ww < 8; ++ww) sacc += sm[L_PS + ww * WID + tid];
          sm[L_HA + tid] = tanhf(sacc);
        }
        __syncthreads();

        // ---- L3: k = W3 @ hA + b3; streamed, rows 1KB-aligned
        {
          const float4* h4 = (const float4*)(sm + L_HA);
#pragma unroll
          for (int ch = 0; ch < 2; ++ch) {
            const int j = w + 8 * (16 * ch + rr);
            const float4* wr = (const float4*)(W3 + (size_t)j * WID);
            float acc = 0.f;
#pragma unroll
            for (int it = 0; it < 16; ++it) {
              float4 wv = wr[4 * it + c];
              float4 fv = h4[4 * it + c];
              acc = fmaf(wv.x, fv.x, acc);
              acc = fmaf(wv.y, fv.y, acc);
              acc = fmaf(wv.z, fv.z, acc);
              acc = fmaf(wv.w, fv.w, acc);
            }
            acc += __shfl_xor(acc, 1);
            acc += __shfl_xor(acc, 2);
            if (c == 0) sm[L_K + j] = acc + sm[L_B3 + j];
          }
          if (rr == 0) {  // rows 256..263: one per wave
            const int j = 256 + w;
            const float4* wr = (const float4*)(W3 + (size_t)j * WID);
            float acc = 0.f;
#pragma unroll
            for (int it = 0; it < 16; ++it) {
              float4 wv = wr[4 * it + c];
              float4 fv = h4[4 * it + c];
              acc = fmaf(wv.x, fv.x, acc);
              acc = fmaf(wv.y, fv.y, acc);
              acc = fmaf(wv.z, fv.z, acc);
              acc = fmaf(wv.w, fv.w, acc);
            }
            acc += __shfl_xor(acc, 1);
            acc += __shfl_xor(acc, 2);
            if (c == 0) sm[L_K + j] = acc + sm[L_B3 + j];
          }
        }
        __syncthreads();

        // ---- RK combine ----
        if (tid < DD) {
          const float kv = sm[L_K + tid];
          if (s == 0) {
            sm[L_ACC + tid] = (2.0f / 9.0f) * kv;
            sm[L_IN + tid]  = sm[L_Y + tid] + 0.5f * h * kv;
          } else if (s == 1) {
            sm[L_ACC + tid] += (1.0f / 3.0f) * kv;
            sm[L_IN + tid]   = sm[L_Y + tid] + 0.75f * h * kv;
          } else {
            sm[L_Y + tid] += h * (sm[L_ACC + tid] + (4.0f / 9.0f) * kv);
          }
        }
        __syncthreads();
      }
    }
    if (tid < DATA) out[((size_t)b * NT + (t + 1)) * DATA + tid] = sm[L_Y + tid];
  }
}

extern "C" void kernel_launch(void* const* d_in, const int* in_sizes, int n_in,
                              void* d_out, int out_size, void* d_ws, size_t ws_size,
                              hipStream_t stream) {
  const float* ts = (const float*)d_in[0];
  const float* xs = (const float*)d_in[1];
  const float* a  = (const float*)d_in[2];
  const float* W0 = (const float*)d_in[3];
  const float* b0 = (const float*)d_in[4];
  const float* W1 = (const float*)d_in[5];
  const float* b1 = (const float*)d_in[6];
  const float* W2 = (const float*)d_in[7];
  const float* b2 = (const float*)d_in[8];
  const float* W3 = (const float*)d_in[9];
  const float* b3 = (const float*)d_in[10];
  float* ws  = (float*)d_ws;
  float* out = (float*)d_out;

  const size_t lds_bytes = LDS_FLOATS * sizeof(float);
  hipFuncSetAttribute(reinterpret_cast<const void*>(node_integrate),
                      hipFuncAttributeMaxDynamicSharedMemorySize,
                      (int)lds_bytes);

  hipLaunchKernelGGL(prep, dim3(64), dim3(256), 0, stream, W0, W1, W2, ws);
  hipLaunchKernelGGL(node_integrate, dim3(NB), dim3(NTH), lds_bytes, stream,
                     ts, xs, a, b0, b1, b2, b3, W3, ws, out);
}

// Round 7
// 22552.385 us; speedup vs baseline: 2.2856x; 2.2856x over previous
//
#include <hip/hip_runtime.h>
#include <cmath>

#define NB   256
#define NT   64
#define DATA 256
#define DD   264
#define DDP  288     // W0 rows padded to 288 floats (1152B = 9 x 128B lines)
#define WID  256
#define NSUB 4
#define NTH  256     // 4 waves; 1 block/CU; 512-VGPR ceiling
#define PI_F 3.14159265358979323846f

// ---- d_ws float offsets ----
#define WS_W0P 0                      // [256][288] padded row-major W0
#define WS_W1T (WS_W0P + 256 * DDP)   // [256][256] k-major W1 (W1T[k][j]=W1[j][k])
#define WS_W2T (WS_W1T + 256 * 256)   // [256][256] k-major W2

// ---- LDS float offsets ----
#define L_W1LO 0          // [128][256] k-major W1 rows 0..127 = 32768
#define L_PSA  32768      // [4][256]
#define L_PSB  33792      // [4][256]
#define L_YA   34816      // 288 each from here on
#define L_YB   35104
#define L_INA  35392
#define L_INB  35680
#define L_KA   35968
#define L_KB   36256
#define L_ACCA 36544
#define L_ACCB 36832
#define L_HAA  37120
#define L_HAB  37408
#define L_HBA  37696
#define L_HBB  37984
#define L_B0   38272      // 256
#define L_B1   38528      // 256
#define L_B2   38784      // 256
#define L_B3   39040      // 288
#define LDS_FLOATS 39328  // 157,312 B -> 1 block/CU

__global__ void prep(const float* __restrict__ W0, const float* __restrict__ W1,
                     const float* __restrict__ W2, float* __restrict__ ws) {
  int tid = blockIdx.x * blockDim.x + threadIdx.x;
  int stride = gridDim.x * blockDim.x;
  for (int i = tid; i < 256 * DDP; i += stride) {
    int j = i / DDP, m = i - j * DDP;
    ws[WS_W0P + i] = (m < DD) ? W0[j * DD + m] : 0.f;
  }
  for (int i = tid; i < 256 * 256; i += stride) {
    int k = i >> 8, j = i & 255;
    ws[WS_W1T + i] = W1[j * 256 + k];
    ws[WS_W2T + i] = W2[j * 256 + k];
  }
}

// 256 threads, launch_bounds(256,1): 1 block/CU, 1 wave/SIMD, 512-VGPR cap.
// W2 lives in 256 literal-indexed VGPRs; demand ~350 << 450 (no-spill zone).
__global__ __launch_bounds__(NTH, 1) void node_integrate(
    const float* __restrict__ ts, const float* __restrict__ xs,
    const float* __restrict__ a_sample,
    const float* __restrict__ b0g, const float* __restrict__ b1g,
    const float* __restrict__ b2g, const float* __restrict__ b3g,
    const float* __restrict__ W3, const float* __restrict__ ws,
    float* __restrict__ out) {
  extern __shared__ float sm[];
  const int blk = blockIdx.x;       // 0..127
  const int bA = 2 * blk, bB = 2 * blk + 1;
  const int tid = threadIdx.x;
  const int w = tid >> 6;           // wave 0..3
  const int l = tid & 63;
  const int rr = l >> 3;            // row-slot 0..7
  const int c = l & 7;              // eighth-row 0..7

  // ---- one-time fills ----
  for (int i = tid; i < 256; i += NTH) {
    sm[L_B0 + i] = b0g[i];
    sm[L_B1 + i] = b1g[i];
    sm[L_B2 + i] = b2g[i];
  }
  for (int i = tid; i < DDP; i += NTH) sm[L_B3 + i] = (i < DD) ? b3g[i] : 0.f;
  {
    const float4* src = (const float4*)(ws + WS_W1T);
    float4* dst = (float4*)(sm + L_W1LO);
    for (int i = tid; i < 128 * 64; i += NTH) dst[i] = src[i];
  }
  // W2 register cache: wave w holds k = 4*i + w, lane l holds cols 4l..4l+3.
  float4 w2r[64];
  {
    const float4* w2t4 = (const float4*)(ws + WS_W2T);
#pragma unroll
    for (int i = 0; i < 64; ++i) w2r[i] = w2t4[(4 * i + w) * 64 + l];
  }
  // y0 = concat(a * exp(-0.1*t0) * sin(pi*x), zeros); pads [264,288) stay 0
  {
    const float t0 = ts[0];
    const float sA = a_sample[bA] * expf(-0.1f * t0);
    const float sB = a_sample[bB] * expf(-0.1f * t0);
    for (int i = tid; i < DDP; i += NTH) {
      float vA = 0.f, vB = 0.f;
      if (i < DATA) {
        vA = sA * sinf(PI_F * xs[(size_t)bA * DATA + i]);
        vB = sB * sinf(PI_F * xs[(size_t)bB * DATA + i]);
      }
      sm[L_YA + i] = vA;
      sm[L_YB + i] = vB;
      sm[L_INA + i] = 0.f;
      sm[L_INB + i] = 0.f;
    }
  }
  __syncthreads();

  if (tid < DATA) {
    out[((size_t)bA * NT) * DATA + tid] = sm[L_YA + tid];
    out[((size_t)bB * NT) * DATA + tid] = sm[L_YB + tid];
  }

  const float* W0p = ws + WS_W0P;
  const float4* w1hi4 = (const float4*)(ws + WS_W1T);

#pragma unroll 1
  for (int t = 0; t < NT - 1; ++t) {
    const float dt = ts[t + 1] - ts[t];
    const float h = dt * (1.0f / NSUB);
#pragma unroll 1
    for (int sub = 0; sub < NSUB; ++sub) {
#pragma unroll 1
      for (int s = 0; s < 3; ++s) {
        const float4* finA4 = (const float4*)(sm + ((s == 0) ? L_YA : L_INA));
        const float4* finB4 = (const float4*)(sm + ((s == 0) ? L_YB : L_INB));

        // ---- L0: hA* = tanh(W0 @ fin + b0); 8 rows x 128B per wave-instr
#pragma unroll 1
        for (int sw = 0; sw < 8; ++sw) {
          const int j = 32 * sw + 8 * w + rr;
          const float4* wr = (const float4*)(W0p + j * DDP);
          float aA = 0.f, aB = 0.f;
#pragma unroll
          for (int it = 0; it < 9; ++it) {
            float4 wv = wr[8 * it + c];
            float4 fA = finA4[8 * it + c];
            float4 fB = finB4[8 * it + c];
            aA = fmaf(wv.x, fA.x, aA); aA = fmaf(wv.y, fA.y, aA);
            aA = fmaf(wv.z, fA.z, aA); aA = fmaf(wv.w, fA.w, aA);
            aB = fmaf(wv.x, fB.x, aB); aB = fmaf(wv.y, fB.y, aB);
            aB = fmaf(wv.z, fB.z, aB); aB = fmaf(wv.w, fB.w, aB);
          }
          aA += __shfl_xor(aA, 1); aA += __shfl_xor(aA, 2); aA += __shfl_xor(aA, 4);
          aB += __shfl_xor(aB, 1); aB += __shfl_xor(aB, 2); aB += __shfl_xor(aB, 4);
          if (c == 0) {
            const float bb = sm[L_B0 + j];
            sm[L_HAA + j] = tanhf(aA + bb);
            sm[L_HAB + j] = tanhf(aB + bb);
          }
        }
        __syncthreads();

        // ---- L1: hB* = tanh(W1 @ hA* + b1); k<128 from LDS, k>=128 streamed
        {
          float4 aA; aA.x = aA.y = aA.z = aA.w = 0.f;
          float4 aB = aA;
          const float4* w1lo4 = (const float4*)(sm + L_W1LO);
#pragma unroll
          for (int i = 0; i < 32; ++i) {
            const int k = 4 * i + w;
            const float4 wv = w1lo4[k * 64 + l];
            const float fA = sm[L_HAA + k];
            const float fB = sm[L_HAB + k];
            aA.x = fmaf(wv.x, fA, aA.x); aA.y = fmaf(wv.y, fA, aA.y);
            aA.z = fmaf(wv.z, fA, aA.z); aA.w = fmaf(wv.w, fA, aA.w);
            aB.x = fmaf(wv.x, fB, aB.x); aB.y = fmaf(wv.y, fB, aB.y);
            aB.z = fmaf(wv.z, fB, aB.z); aB.w = fmaf(wv.w, fB, aB.w);
          }
#pragma unroll 8
          for (int i = 0; i < 32; ++i) {
            const int k = 128 + 4 * i + w;
            const float4 wv = w1hi4[k * 64 + l];    // coalesced 1KB/instr
            const float fA = sm[L_HAA + k];
            const float fB = sm[L_HAB + k];
            aA.x = fmaf(wv.x, fA, aA.x); aA.y = fmaf(wv.y, fA, aA.y);
            aA.z = fmaf(wv.z, fA, aA.z); aA.w = fmaf(wv.w, fA, aA.w);
            aB.x = fmaf(wv.x, fB, aB.x); aB.y = fmaf(wv.y, fB, aB.y);
            aB.z = fmaf(wv.z, fB, aB.z); aB.w = fmaf(wv.w, fB, aB.w);
          }
          ((float4*)(sm + L_PSA + w * 256))[l] = aA;
          ((float4*)(sm + L_PSB + w * 256))[l] = aB;
        }
        __syncthreads();
        if (tid < 256) {
          float sA = sm[L_B1 + tid];
          float sB = sA;
#pragma unroll
          for (int ww = 0; ww < 4; ++ww) {
            sA += sm[L_PSA + ww * 256 + tid];
            sB += sm[L_PSB + ww * 256 + tid];
          }
          sm[L_HBA + tid] = tanhf(sA);
          sm[L_HBB + tid] = tanhf(sB);
        }
        __syncthreads();

        // ---- L2: hA* = tanh(W2 @ hB* + b2); all-register W2
        {
          float4 aA; aA.x = aA.y = aA.z = aA.w = 0.f;
          float4 aB = aA;
#pragma unroll
          for (int i = 0; i < 64; ++i) {
            const int k = 4 * i + w;
            const float fA = sm[L_HBA + k];
            const float fB = sm[L_HBB + k];
            aA.x = fmaf(w2r[i].x, fA, aA.x); aA.y = fmaf(w2r[i].y, fA, aA.y);
            aA.z = fmaf(w2r[i].z, fA, aA.z); aA.w = fmaf(w2r[i].w, fA, aA.w);
            aB.x = fmaf(w2r[i].x, fB, aB.x); aB.y = fmaf(w2r[i].y, fB, aB.y);
            aB.z = fmaf(w2r[i].z, fB, aB.z); aB.w = fmaf(w2r[i].w, fB, aB.w);
          }
          ((float4*)(sm + L_PSA + w * 256))[l] = aA;
          ((float4*)(sm + L_PSB + w * 256))[l] = aB;
        }
        __syncthreads();
        if (tid < 256) {
          float sA = sm[L_B2 + tid];
          float sB = sA;
#pragma unroll
          for (int ww = 0; ww < 4; ++ww) {
            sA += sm[L_PSA + ww * 256 + tid];
            sB += sm[L_PSB + ww * 256 + tid];
          }
          sm[L_HAA + tid] = tanhf(sA);
          sm[L_HAB + tid] = tanhf(sB);
        }
        __syncthreads();

        // ---- L3: k = W3 @ hA* + b3; 8 rows x 128B per wave-instr
        {
          const float4* hA4 = (const float4*)(sm + L_HAA);
          const float4* hB4 = (const float4*)(sm + L_HAB);
#pragma unroll 1
          for (int sw = 0; sw < 8; ++sw) {
            const int j = 32 * sw + 8 * w + rr;
            const float4* wr = (const float4*)(W3 + (size_t)j * WID);
            float aA = 0.f, aB = 0.f;
#pragma unroll
            for (int it = 0; it < 8; ++it) {
              float4 wv = wr[8 * it + c];
              float4 fA = hA4[8 * it + c];
              float4 fB = hB4[8 * it + c];
              aA = fmaf(wv.x, fA.x, aA); aA = fmaf(wv.y, fA.y, aA);
              aA = fmaf(wv.z, fA.z, aA); aA = fmaf(wv.w, fA.w, aA);
              aB = fmaf(wv.x, fB.x, aB); aB = fmaf(wv.y, fB.y, aB);
              aB = fmaf(wv.z, fB.z, aB); aB = fmaf(wv.w, fB.w, aB);
            }
            aA += __shfl_xor(aA, 1); aA += __shfl_xor(aA, 2); aA += __shfl_xor(aA, 4);
            aB += __shfl_xor(aB, 1); aB += __shfl_xor(aB, 2); aB += __shfl_xor(aB, 4);
            if (c == 0) {
              const float bb = sm[L_B3 + j];
              sm[L_KA + j] = aA + bb;
              sm[L_KB + j] = aB + bb;
            }
          }
          if (w < 2) {  // tail rows 256..263: wave0 -> A, wave1 -> B
            const int j = 256 + rr;
            const float4* wr = (const float4*)(W3 + (size_t)j * WID);
            const float4* hv = (w == 0) ? hA4 : hB4;
            float a = 0.f;
#pragma unroll
            for (int it = 0; it < 8; ++it) {
              float4 wv = wr[8 * it + c];
              float4 fv = hv[8 * it + c];
              a = fmaf(wv.x, fv.x, a); a = fmaf(wv.y, fv.y, a);
              a = fmaf(wv.z, fv.z, a); a = fmaf(wv.w, fv.w, a);
            }
            a += __shfl_xor(a, 1); a += __shfl_xor(a, 2); a += __shfl_xor(a, 4);
            if (c == 0) {
              const int dst = (w == 0) ? L_KA : L_KB;
              sm[dst + j] = a + sm[L_B3 + j];
            }
          }
        }
        __syncthreads();

        // ---- RK combine (both elements) ----
        for (int i = tid; i < DD; i += NTH) {
          const float kA = sm[L_KA + i];
          const float kB = sm[L_KB + i];
          if (s == 0) {
            sm[L_ACCA + i] = (2.0f / 9.0f) * kA;
            sm[L_ACCB + i] = (2.0f / 9.0f) * kB;
            sm[L_INA + i] = sm[L_YA + i] + 0.5f * h * kA;
            sm[L_INB + i] = sm[L_YB + i] + 0.5f * h * kB;
          } else if (s == 1) {
            sm[L_ACCA + i] += (1.0f / 3.0f) * kA;
            sm[L_ACCB + i] += (1.0f / 3.0f) * kB;
            sm[L_INA + i] = sm[L_YA + i] + 0.75f * h * kA;
            sm[L_INB + i] = sm[L_YB + i] + 0.75f * h * kB;
          } else {
            sm[L_YA + i] += h * (sm[L_ACCA + i] + (4.0f / 9.0f) * kA);
            sm[L_YB + i] += h * (sm[L_ACCB + i] + (4.0f / 9.0f) * kB);
          }
        }
        __syncthreads();
      }
    }
    if (tid < DATA) {
      out[((size_t)bA * NT + (t + 1)) * DATA + tid] = sm[L_YA + tid];
      out[((size_t)bB * NT + (t + 1)) * DATA + tid] = sm[L_YB + tid];
    }
  }
}

extern "C" void kernel_launch(void* const* d_in, const int* in_sizes, int n_in,
                              void* d_out, int out_size, void* d_ws, size_t ws_size,
                              hipStream_t stream) {
  const float* ts = (const float*)d_in[0];
  const float* xs = (const float*)d_in[1];
  const float* a  = (const float*)d_in[2];
  const float* W0 = (const float*)d_in[3];
  const float* b0 = (const float*)d_in[4];
  const float* W1 = (const float*)d_in[5];
  const float* b1 = (const float*)d_in[6];
  const float* W2 = (const float*)d_in[7];
  const float* b2 = (const float*)d_in[8];
  const float* W3 = (const float*)d_in[9];
  const float* b3 = (const float*)d_in[10];
  float* ws  = (float*)d_ws;
  float* out = (float*)d_out;

  const size_t lds_bytes = LDS_FLOATS * sizeof(float);
  hipFuncSetAttribute(reinterpret_cast<const void*>(node_integrate),
                      hipFuncAttributeMaxDynamicSharedMemorySize,
                      (int)lds_bytes);

  hipLaunchKernelGGL(prep, dim3(64), dim3(256), 0, stream, W0, W1, W2, ws);
  hipLaunchKernelGGL(node_integrate, dim3(NB / 2), dim3(NTH), lds_bytes, stream,
                     ts, xs, a, b0, b1, b2, b3, W3, ws, out);
}

// Round 9
// 8455.463 us; speedup vs baseline: 6.0961x; 2.6672x over previous
//
#include <hip/hip_runtime.h>
#include <cmath>

#define NB   256
#define NT   64
#define DATA 256
#define DD   264
#define WID  256
#define NSUB 4
#define NTH  512
#define PI_F 3.14159265358979323846f

// ---- d_ws float offsets (k-major transposed weights) ----
#define WS_W0T 0                          // [264][256]
#define WS_W1T (WS_W0T + DD * WID)        // [256][256]
#define WS_W2T (WS_W1T + WID * WID)       // [256][256]
#define W3NP   272
#define WS_W3T (WS_W2T + WID * WID)       // [256][272] (cols 264..271 zero)

// ---- LDS float offsets ----
#define L_W1LO 0                          // [128][256] k-major W1 rows 0..127
#define L_PS   (L_W1LO + 128 * 256)       // [8][272]
#define L_Y    (L_PS + 8 * 272)           // 272
#define L_IN   (L_Y + 272)                // 272
#define L_ACC  (L_IN + 272)               // 272
#define L_HA   (L_ACC + 272)              // 272
#define L_HB   (L_HA + 272)               // 272
#define L_B0   (L_HB + 272)               // 256
#define L_B1   (L_B0 + 256)               // 256
#define L_B2   (L_B1 + 256)               // 256
#define L_B3   (L_B2 + 256)               // 272
#define LDS_FLOATS (L_B3 + 272)           // 37344 fl = 149,376 B -> 1 block/CU

#define FMA4(acc, wv, fk)                                                     \
  acc.x = fmaf((wv).x, (fk), acc.x);                                          \
  acc.y = fmaf((wv).y, (fk), acc.y);                                          \
  acc.z = fmaf((wv).z, (fk), acc.z);                                          \
  acc.w = fmaf((wv).w, (fk), acc.w);

__global__ void prep(const float* __restrict__ W0, const float* __restrict__ W1,
                     const float* __restrict__ W2, const float* __restrict__ W3,
                     float* __restrict__ ws) {
  int tid = blockIdx.x * blockDim.x + threadIdx.x;
  int stride = gridDim.x * blockDim.x;
  for (int i = tid; i < DD * WID; i += stride) {        // W0T[k][j] = W0[j][k]
    int k = i >> 8, j = i & 255;
    ws[WS_W0T + i] = W0[j * DD + k];
  }
  for (int i = tid; i < WID * WID; i += stride) {       // W1T, W2T
    int k = i >> 8, j = i & 255;
    ws[WS_W1T + i] = W1[j * WID + k];
    ws[WS_W2T + i] = W2[j * WID + k];
  }
  for (int i = tid; i < WID * W3NP; i += stride) {      // W3T[k][j] = W3[j][k]
    int k = i / W3NP, j = i - k * W3NP;
    ws[WS_W3T + i] = (j < DD) ? W3[j * WID + k] : 0.f;
  }
}

// 512 threads = 8 waves = 2 waves/SIMD -> VGPR cap 256. Register demand is
// engineered to ~200 (W2 cache = 128 regs, unroll-4 stream temps), so no
// spill (R4-R6 failed because demand ~260-320 > the 8-wave cap of 256).
__global__ __launch_bounds__(NTH, 2) void node_integrate(
    const float* __restrict__ ts, const float* __restrict__ xs,
    const float* __restrict__ a_sample,
    const float* __restrict__ b0g, const float* __restrict__ b1g,
    const float* __restrict__ b2g, const float* __restrict__ b3g,
    const float* __restrict__ ws, float* __restrict__ out) {
  extern __shared__ float sm[];
  const int b   = blockIdx.x;     // one batch element per block
  const int tid = threadIdx.x;
  const int w   = tid >> 6;       // wave 0..7
  const int l   = tid & 63;       // lane

  const float4* __restrict__ w0t4 = (const float4*)(ws + WS_W0T);
  const float4* __restrict__ w1t4 = (const float4*)(ws + WS_W1T);
  const float4* __restrict__ w3t4 = (const float4*)(ws + WS_W3T);

  // ---- one-time fills ----
  for (int i = tid; i < 256; i += NTH) {
    sm[L_B0 + i] = b0g[i];
    sm[L_B1 + i] = b1g[i];
    sm[L_B2 + i] = b2g[i];
  }
  for (int i = tid; i < 272; i += NTH) sm[L_B3 + i] = (i < DD) ? b3g[i] : 0.f;
  {
    const float4* src = (const float4*)(ws + WS_W1T);   // rows k=0..127
    float4* dst = (float4*)(sm + L_W1LO);
    for (int i = tid; i < 128 * 64; i += NTH) dst[i] = src[i];
  }
  // W2 register cache: wave w holds k = w + 8i (i<32), lane l cols 4l..4l+3.
  float4 w2r[32];
  {
    const float4* w2t4 = (const float4*)(ws + WS_W2T);
#pragma unroll
    for (int i = 0; i < 32; ++i) w2r[i] = w2t4[(w + 8 * i) * 64 + l];
  }
  // y0 = concat(a * exp(-0.1*t0) * sin(pi*x), zeros(AUG)); pads stay 0
  {
    const float sc = a_sample[b] * expf(-0.1f * ts[0]);
    for (int i = tid; i < 272; i += NTH) {
      float v = 0.f;
      if (i < DATA) v = sc * sinf(PI_F * xs[(size_t)b * DATA + i]);
      sm[L_Y + i]  = v;
      sm[L_IN + i] = 0.f;
    }
  }
  __syncthreads();

  if (tid < DATA) out[((size_t)b * NT) * DATA + tid] = sm[L_Y + tid];

  float4* ps4 = (float4*)(sm + L_PS);     // stride 68 float4 per wave

#pragma unroll 1
  for (int t = 0; t < NT - 1; ++t) {
    const float dt = ts[t + 1] - ts[t];
    const float h  = dt * (1.0f / NSUB);
#pragma unroll 1
    for (int sub = 0; sub < NSUB; ++sub) {
#pragma unroll 1
      for (int s = 0; s < 3; ++s) {
        const float* finp = sm + ((s == 0) ? L_Y : L_IN);

        // ---- L0: hA = tanh(W0 @ fin + b0); streamed k-major, K=264
        {
          float4 acc; acc.x = acc.y = acc.z = acc.w = 0.f;
#pragma unroll 4
          for (int i = 0; i < 33; ++i) {
            const int k = w + 8 * i;          // < 264
            const float fk = finp[k];
            const float4 wv = w0t4[k * 64 + l];
            FMA4(acc, wv, fk)
          }
          ps4[w * 68 + l] = acc;
        }
        __syncthreads();
        if (tid < 256) {
          float sv = sm[L_B0 + tid];
#pragma unroll
          for (int ww = 0; ww < 8; ++ww) sv += sm[L_PS + ww * 272 + tid];
          sm[L_HA + tid] = tanhf(sv);
        }
        __syncthreads();

        // ---- L1: hB = tanh(W1 @ hA + b1); k<128 LDS, k>=128 streamed
        {
          float4 acc; acc.x = acc.y = acc.z = acc.w = 0.f;
          const float4* w1lo4 = (const float4*)(sm + L_W1LO);
#pragma unroll 4
          for (int i = 0; i < 16; ++i) {
            const int k = w + 8 * i;          // < 128
            const float fk = sm[L_HA + k];
            const float4 wv = w1lo4[k * 64 + l];
            FMA4(acc, wv, fk)
          }
#pragma unroll 4
          for (int i = 16; i < 32; ++i) {
            const int k = w + 8 * i;          // 128..255
            const float fk = sm[L_HA + k];
            const float4 wv = w1t4[k * 64 + l];
            FMA4(acc, wv, fk)
          }
          ps4[w * 68 + l] = acc;
        }
        __syncthreads();
        if (tid < 256) {
          float sv = sm[L_B1 + tid];
#pragma unroll
          for (int ww = 0; ww < 8; ++ww) sv += sm[L_PS + ww * 272 + tid];
          sm[L_HB + tid] = tanhf(sv);
        }
        __syncthreads();

        // ---- L2: hA = tanh(W2 @ hB + b2); all-register W2
        {
          float4 acc; acc.x = acc.y = acc.z = acc.w = 0.f;
#pragma unroll
          for (int i = 0; i < 32; ++i) {
            const float fk = sm[L_HB + w + 8 * i];
            FMA4(acc, w2r[i], fk)
          }
          ps4[w * 68 + l] = acc;
        }
        __syncthreads();
        if (tid < 256) {
          float sv = sm[L_B2 + tid];
#pragma unroll
          for (int ww = 0; ww < 8; ++ww) sv += sm[L_PS + ww * 272 + tid];
          sm[L_HA + tid] = tanhf(sv);
        }
        __syncthreads();

        // ---- L3 + RK: kv = W3 @ hA + b3; streamed k-major [256][272]
        {
          float4 acc; acc.x = acc.y = acc.z = acc.w = 0.f;
          float4 accx; accx.x = accx.y = accx.z = accx.w = 0.f;
#pragma unroll 4
          for (int i = 0; i < 32; ++i) {
            const int k = w + 8 * i;
            const float fk = sm[L_HA + k];
            const float4 wv = w3t4[k * 68 + l];
            FMA4(acc, wv, fk)
            if (l < 4) {
              const float4 wx = w3t4[k * 68 + 64 + l];
              FMA4(accx, wx, fk)
            }
          }
          ps4[w * 68 + l] = acc;
          if (l < 4) ps4[w * 68 + 64 + l] = accx;
        }
        __syncthreads();
        if (tid < DD) {
          float kv = sm[L_B3 + tid];
#pragma unroll
          for (int ww = 0; ww < 8; ++ww) kv += sm[L_PS + ww * 272 + tid];
          if (s == 0) {
            sm[L_ACC + tid] = (2.0f / 9.0f) * kv;
            sm[L_IN + tid]  = sm[L_Y + tid] + 0.5f * h * kv;
          } else if (s == 1) {
            sm[L_ACC + tid] += (1.0f / 3.0f) * kv;
            sm[L_IN + tid]   = sm[L_Y + tid] + 0.75f * h * kv;
          } else {
            sm[L_Y + tid] += h * (sm[L_ACC + tid] + (4.0f / 9.0f) * kv);
          }
        }
        __syncthreads();
      }
    }
    if (tid < DATA) out[((size_t)b * NT + (t + 1)) * DATA + tid] = sm[L_Y + tid];
  }
}

extern "C" void kernel_launch(void* const* d_in, const int* in_sizes, int n_in,
                              void* d_out, int out_size, void* d_ws, size_t ws_size,
                              hipStream_t stream) {
  const float* ts = (const float*)d_in[0];
  const float* xs = (const float*)d_in[1];
  const float* a  = (const float*)d_in[2];
  const float* W0 = (const float*)d_in[3];
  const float* b0 = (const float*)d_in[4];
  const float* W1 = (const float*)d_in[5];
  const float* b1 = (const float*)d_in[6];
  const float* W2 = (const float*)d_in[7];
  const float* b2 = (const float*)d_in[8];
  const float* W3 = (const float*)d_in[9];
  const float* b3 = (const float*)d_in[10];
  float* ws  = (float*)d_ws;
  float* out = (float*)d_out;

  const size_t lds_bytes = LDS_FLOATS * sizeof(float);
  hipFuncSetAttribute(reinterpret_cast<const void*>(node_integrate),
                      hipFuncAttributeMaxDynamicSharedMemorySize,
                      (int)lds_bytes);

  hipLaunchKernelGGL(prep, dim3(256), dim3(256), 0, stream, W0, W1, W2, W3, ws);
  hipLaunchKernelGGL(node_integrate, dim3(NB), dim3(NTH), lds_bytes, stream,
                     ts, xs, a, b0, b1, b2, b3, ws, out);
}